// Round 1
// baseline (379.669 us; speedup 1.0000x reference)
//
#include <hip/hip_runtime.h>
#include <math.h>

#define NREG  8
#define HDIM  128
#define NDEPTH 3
#define TP    64      // points per workgroup tile
#define STRIP 32      // W rows staged per LDS strip
#define W0F   30.0f

// ---------------- routing helpers ----------------

__device__ __forceinline__ int region_of(float X, float Y, float Z, bool* valid) {
    *valid = (X >= 0.f) & (X <= 1.f) & (Y >= 0.f) & (Y <= 1.f) & (Z >= 0.f) & (Z <= 1.f);
    // box r = i*4 + j*2 + k ; ties at 0.5 belong to the lower box (argmax picks first)
    int i = (X > 0.5f) ? 1 : 0;
    int j = (Y > 0.5f) ? 1 : 0;
    int k = (Z > 0.5f) ? 1 : 0;
    return i * 4 + j * 2 + k;
}

// ws int layout: [0..7] counts, [8..16] offsets(exclusive, +total), [20..27] cursors
__global__ __launch_bounds__(256) void k_count(const float* __restrict__ x, int n,
                                               int* __restrict__ ws) {
    __shared__ int h[NREG];
    if (threadIdx.x < NREG) h[threadIdx.x] = 0;
    __syncthreads();
    int i = blockIdx.x * 256 + threadIdx.x;
    if (i < n) {
        float X = x[3*i], Y = x[3*i+1], Z = x[3*i+2];
        bool valid;
        int r = region_of(X, Y, Z, &valid);
        if (valid) atomicAdd(&h[r], 1);
    }
    __syncthreads();
    if (threadIdx.x < NREG) atomicAdd(&ws[threadIdx.x], h[threadIdx.x]);
}

__global__ void k_prefix(int* __restrict__ ws) {
    if (threadIdx.x == 0) {
        int acc = 0;
        for (int r = 0; r < NREG; ++r) {
            ws[8 + r] = acc;      // offsets
            ws[20 + r] = acc;     // cursors
            acc += ws[r];
        }
        ws[8 + NREG] = acc;
    }
}

__global__ __launch_bounds__(256) void k_scatter(const float* __restrict__ x, int n,
                                                 int* __restrict__ ws,
                                                 int* __restrict__ idx,
                                                 float* __restrict__ out) {
    int i = blockIdx.x * 256 + threadIdx.x;
    if (i >= n) return;
    float X = x[3*i], Y = x[3*i+1], Z = x[3*i+2];
    bool valid;
    int r = region_of(X, Y, Z, &valid);
    if (valid) {
        int pos = atomicAdd(&ws[20 + r], 1);
        idx[pos] = i;
    } else {
        out[i] = 0.0f;   // points outside all boxes stay zero
    }
}

// ---------------- fused per-region SIREN MLP ----------------
// One WG = 64 points of one region. h[128][64] resident in LDS; W streamed
// through a 32x128 LDS strip. Thread tile: 4 points x 8 channels.

__global__ __launch_bounds__(256, 3) void k_mlp(
    const float* __restrict__ x,
    const float* __restrict__ W_in,  const float* __restrict__ b_in,
    const float* __restrict__ W_h,   const float* __restrict__ b_h,
    const float* __restrict__ W_out, const float* __restrict__ b_out,
    const float* __restrict__ scale, const float* __restrict__ boxes,
    const int* __restrict__ offsets, const int* __restrict__ idx,
    float* __restrict__ out)
{
    __shared__ __align__(16) float hA[HDIM][TP];      // 32 KB  [channel][point]
    __shared__ __align__(16) float Ws[STRIP * HDIM];  // 16 KB
    __shared__ float bias[HDIM];
    __shared__ float xn_s[TP][3];
    __shared__ int   gidx[TP];

    const int tid = threadIdx.x;

    // map flat block id -> (region, tile)
    int r = -1, base = 0, cnt = 0;
    {
        int bid = blockIdx.x, acc = 0;
        for (int rr = 0; rr < NREG; ++rr) {
            int o0 = offsets[rr], o1 = offsets[rr + 1];
            int c = o1 - o0;
            int t = (c + TP - 1) / TP;
            if (bid < acc + t) {
                int tile = bid - acc;
                r = rr; base = o0 + tile * TP; cnt = c - tile * TP;
                break;
            }
            acc += t;
        }
    }
    if (r < 0) return;                 // uniform across the block
    if (cnt > TP) cnt = TP;

    // ---- stage points (normalized coords) + gather indices ----
    if (tid < TP) {
        int g = (tid < cnt) ? idx[base + tid] : -1;
        gidx[tid] = g;
        float xs[3] = {0.f, 0.f, 0.f};
        if (g >= 0) { xs[0] = x[3*g]; xs[1] = x[3*g+1]; xs[2] = x[3*g+2]; }
        #pragma unroll
        for (int d = 0; d < 3; ++d) {
            float lo = boxes[r*6 + d*2 + 0];
            float hi = boxes[r*6 + d*2 + 1];
            float xn = (2.0f * (xs[d] - lo) / (hi - lo) - 1.0f) * scale[r*3 + d];
            xn_s[tid][d] = (g >= 0) ? xn : 0.0f;
        }
    }
    // stage W_in (3x128) + b_in
    for (int i = tid; i < 3 * HDIM; i += 256) Ws[i] = W_in[r * 3 * HDIM + i];
    for (int i = tid; i < HDIM; i += 256)     bias[i] = b_in[r * HDIM + i];
    __syncthreads();

    const int pg = tid & 15;     // 16 point-groups
    const int kg = tid >> 4;     // 16 channel-groups
    const int p0 = pg * 4;
    const int k0 = kg * 8;

    // ---- input layer: h = sin(30*(xn @ W_in + b_in)) ----
    {
        float xm[4][3];
        #pragma unroll
        for (int m = 0; m < 4; ++m) {
            xm[m][0] = xn_s[p0 + m][0];
            xm[m][1] = xn_s[p0 + m][1];
            xm[m][2] = xn_s[p0 + m][2];
        }
        #pragma unroll
        for (int kc = 0; kc < 8; ++kc) {
            int k = k0 + kc;
            float w0 = Ws[0 * HDIM + k];
            float w1 = Ws[1 * HDIM + k];
            float w2 = Ws[2 * HDIM + k];
            float bk = bias[k];
            float v[4];
            #pragma unroll
            for (int m = 0; m < 4; ++m) {
                float a = fmaf(xm[m][0], w0, fmaf(xm[m][1], w1, fmaf(xm[m][2], w2, bk)));
                v[m] = sinf(W0F * a);
            }
            *(float4*)&hA[k][p0] = make_float4(v[0], v[1], v[2], v[3]);
        }
    }

    // ---- hidden layers ----
    for (int l = 0; l < NDEPTH; ++l) {
        const float* Wl = W_h + (size_t)(r * NDEPTH + l) * HDIM * HDIM;
        const float* bl = b_h + (r * NDEPTH + l) * HDIM;
        float accv[4][8];
        #pragma unroll
        for (int m = 0; m < 4; ++m)
            #pragma unroll
            for (int kc = 0; kc < 8; ++kc) accv[m][kc] = 0.f;

        for (int s = 0; s < HDIM / STRIP; ++s) {
            __syncthreads();   // previous strip compute / prev-layer Ws reads done
            // load 32x128 W strip (linear copy, coalesced float4)
            #pragma unroll
            for (int i = 0; i < (STRIP * HDIM) / (256 * 4); ++i) {
                int off = (i * 256 + tid) * 4;
                *(float4*)&Ws[off] = *(const float4*)(Wl + (size_t)s * STRIP * HDIM + off);
            }
            if (s == 0)
                for (int i = tid; i < HDIM; i += 256) bias[i] = bl[i];
            __syncthreads();

            #pragma unroll 8
            for (int j = 0; j < STRIP; ++j) {
                int jj = s * STRIP + j;
                float4 a4 = *(const float4*)&hA[jj][p0];
                float4 wA = *(const float4*)&Ws[j * HDIM + k0];
                float4 wB = *(const float4*)&Ws[j * HDIM + k0 + 4];
                float av[4] = {a4.x, a4.y, a4.z, a4.w};
                float wv[8] = {wA.x, wA.y, wA.z, wA.w, wB.x, wB.y, wB.z, wB.w};
                #pragma unroll
                for (int m = 0; m < 4; ++m)
                    #pragma unroll
                    for (int kc = 0; kc < 8; ++kc)
                        accv[m][kc] = fmaf(av[m], wv[kc], accv[m][kc]);
            }
        }
        __syncthreads();   // all hA reads for this layer complete
        #pragma unroll
        for (int kc = 0; kc < 8; ++kc) {
            int k = k0 + kc;
            float bk = bias[k];
            float v[4];
            #pragma unroll
            for (int m = 0; m < 4; ++m)
                v[m] = sinf(W0F * (accv[m][kc] + bk));
            *(float4*)&hA[k][p0] = make_float4(v[0], v[1], v[2], v[3]);
        }
    }
    __syncthreads();

    // ---- output layer: vis = h @ W_out + b_out ----
    if (tid < HDIM) Ws[tid] = W_out[r * HDIM + tid];
    __syncthreads();
    if (tid < TP) {
        float sacc = 0.f;
        #pragma unroll 8
        for (int k = 0; k < HDIM; ++k)
            sacc = fmaf(hA[k][tid], Ws[k], sacc);
        sacc += b_out[r];
        int g = gidx[tid];
        if (g >= 0) out[g] = sacc;
    }
}

// ---------------- launcher ----------------

extern "C" void kernel_launch(void* const* d_in, const int* in_sizes, int n_in,
                              void* d_out, int out_size, void* d_ws, size_t ws_size,
                              hipStream_t stream) {
    const float* x      = (const float*)d_in[0];
    const float* W_in   = (const float*)d_in[1];
    const float* b_in   = (const float*)d_in[2];
    const float* W_h    = (const float*)d_in[3];
    const float* b_h    = (const float*)d_in[4];
    const float* W_out  = (const float*)d_in[5];
    const float* b_out  = (const float*)d_in[6];
    const float* scale  = (const float*)d_in[7];
    const float* boxes  = (const float*)d_in[8];
    float* out = (float*)d_out;

    int n = in_sizes[0] / 3;
    int* wsi = (int*)d_ws;
    int* idx = (int*)((char*)d_ws + 256);

    hipMemsetAsync(d_ws, 0, 256, stream);

    int nb = (n + 255) / 256;
    hipLaunchKernelGGL(k_count,   dim3(nb), dim3(256), 0, stream, x, n, wsi);
    hipLaunchKernelGGL(k_prefix,  dim3(1),  dim3(64),  0, stream, wsi);
    hipLaunchKernelGGL(k_scatter, dim3(nb), dim3(256), 0, stream, x, n, wsi, idx, out);

    int ntiles = (n + TP - 1) / TP + NREG;
    hipLaunchKernelGGL(k_mlp, dim3(ntiles), dim3(256), 0, stream,
                       x, W_in, b_in, W_h, b_h, W_out, b_out, scale, boxes,
                       wsi + 8, idx, out);
}

// Round 2
// 138.396 us; speedup vs baseline: 2.7433x; 2.7433x over previous
//
#include <hip/hip_runtime.h>
#include <math.h>

#define NREG  8
#define HDIM  128
#define NDEPTH 3
#define TP    64      // points per workgroup tile
#define STRIP 32      // W rows staged per LDS strip
#define W0F   30.0f

// ---------------- routing helpers ----------------

__device__ __forceinline__ int region_of(float X, float Y, float Z, bool* valid) {
    *valid = (X >= 0.f) & (X <= 1.f) & (Y >= 0.f) & (Y <= 1.f) & (Z >= 0.f) & (Z <= 1.f);
    // box r = i*4 + j*2 + k ; ties at 0.5 belong to the lower box (argmax picks first)
    int i = (X > 0.5f) ? 1 : 0;
    int j = (Y > 0.5f) ? 1 : 0;
    int k = (Z > 0.5f) ? 1 : 0;
    return i * 4 + j * 2 + k;
}

// ws int layout: [0..7] counts, [8..16] offsets(exclusive, +total), [20..27] cursors
__global__ __launch_bounds__(256) void k_count(const float* __restrict__ x, int n,
                                               int* __restrict__ ws) {
    __shared__ int h[NREG];
    if (threadIdx.x < NREG) h[threadIdx.x] = 0;
    __syncthreads();
    int i = blockIdx.x * 256 + threadIdx.x;
    if (i < n) {
        float X = x[3*i], Y = x[3*i+1], Z = x[3*i+2];
        bool valid;
        int r = region_of(X, Y, Z, &valid);
        if (valid) atomicAdd(&h[r], 1);
    }
    __syncthreads();
    if (threadIdx.x < NREG) atomicAdd(&ws[threadIdx.x], h[threadIdx.x]);
}

__global__ void k_prefix(int* __restrict__ ws) {
    if (threadIdx.x == 0) {
        int acc = 0;
        for (int r = 0; r < NREG; ++r) {
            ws[8 + r] = acc;      // offsets
            ws[20 + r] = acc;     // cursors
            acc += ws[r];
        }
        ws[8 + NREG] = acc;
    }
}

// Block-aggregated scatter: LDS-rank within block, ONE global atomic per
// (block, region) to reserve a chunk, then direct stores. 2048 global atomics
// total instead of 65536 (which serialized at ~30ns each -> 245us).
__global__ __launch_bounds__(256) void k_scatter(const float* __restrict__ x, int n,
                                                 int* __restrict__ ws,
                                                 int* __restrict__ idx,
                                                 float* __restrict__ out) {
    __shared__ int hist[NREG];
    __shared__ int base[NREG];
    const int tid = threadIdx.x;
    if (tid < NREG) hist[tid] = 0;
    __syncthreads();
    int i = blockIdx.x * 256 + tid;
    int r = 0, rank = 0;
    bool valid = false;
    if (i < n) {
        float X = x[3*i], Y = x[3*i+1], Z = x[3*i+2];
        r = region_of(X, Y, Z, &valid);
        if (valid) rank = atomicAdd(&hist[r], 1);   // within-block rank
        else out[i] = 0.0f;   // points outside all boxes stay zero
    }
    __syncthreads();
    if (tid < NREG) {
        int c = hist[tid];
        base[tid] = c ? atomicAdd(&ws[20 + tid], c) : 0;
    }
    __syncthreads();
    if (valid) idx[base[r] + rank] = i;
}

// ---------------- fused per-region SIREN MLP ----------------
// One WG = 64 points of one region. h[128][64] resident in LDS; W streamed
// through a 32x128 LDS strip. Thread tile: 4 points x 8 channels.

__global__ __launch_bounds__(256, 3) void k_mlp(
    const float* __restrict__ x,
    const float* __restrict__ W_in,  const float* __restrict__ b_in,
    const float* __restrict__ W_h,   const float* __restrict__ b_h,
    const float* __restrict__ W_out, const float* __restrict__ b_out,
    const float* __restrict__ scale, const float* __restrict__ boxes,
    const int* __restrict__ offsets, const int* __restrict__ idx,
    float* __restrict__ out)
{
    __shared__ __align__(16) float hA[HDIM][TP];      // 32 KB  [channel][point]
    __shared__ __align__(16) float Ws[STRIP * HDIM];  // 16 KB
    __shared__ float bias[HDIM];
    __shared__ float xn_s[TP][3];
    __shared__ int   gidx[TP];

    const int tid = threadIdx.x;

    // map flat block id -> (region, tile)
    int r = -1, base = 0, cnt = 0;
    {
        int bid = blockIdx.x, acc = 0;
        for (int rr = 0; rr < NREG; ++rr) {
            int o0 = offsets[rr], o1 = offsets[rr + 1];
            int c = o1 - o0;
            int t = (c + TP - 1) / TP;
            if (bid < acc + t) {
                int tile = bid - acc;
                r = rr; base = o0 + tile * TP; cnt = c - tile * TP;
                break;
            }
            acc += t;
        }
    }
    if (r < 0) return;                 // uniform across the block
    if (cnt > TP) cnt = TP;

    // ---- stage points (normalized coords) + gather indices ----
    if (tid < TP) {
        int g = (tid < cnt) ? idx[base + tid] : -1;
        gidx[tid] = g;
        float xs[3] = {0.f, 0.f, 0.f};
        if (g >= 0) { xs[0] = x[3*g]; xs[1] = x[3*g+1]; xs[2] = x[3*g+2]; }
        #pragma unroll
        for (int d = 0; d < 3; ++d) {
            float lo = boxes[r*6 + d*2 + 0];
            float hi = boxes[r*6 + d*2 + 1];
            float xn = (2.0f * (xs[d] - lo) / (hi - lo) - 1.0f) * scale[r*3 + d];
            xn_s[tid][d] = (g >= 0) ? xn : 0.0f;
        }
    }
    // stage W_in (3x128) + b_in
    for (int i = tid; i < 3 * HDIM; i += 256) Ws[i] = W_in[r * 3 * HDIM + i];
    for (int i = tid; i < HDIM; i += 256)     bias[i] = b_in[r * HDIM + i];
    __syncthreads();

    const int pg = tid & 15;     // 16 point-groups
    const int kg = tid >> 4;     // 16 channel-groups
    const int p0 = pg * 4;
    const int k0 = kg * 8;

    // ---- input layer: h = sin(30*(xn @ W_in + b_in)) ----
    {
        float xm[4][3];
        #pragma unroll
        for (int m = 0; m < 4; ++m) {
            xm[m][0] = xn_s[p0 + m][0];
            xm[m][1] = xn_s[p0 + m][1];
            xm[m][2] = xn_s[p0 + m][2];
        }
        #pragma unroll
        for (int kc = 0; kc < 8; ++kc) {
            int k = k0 + kc;
            float w0 = Ws[0 * HDIM + k];
            float w1 = Ws[1 * HDIM + k];
            float w2 = Ws[2 * HDIM + k];
            float bk = bias[k];
            float v[4];
            #pragma unroll
            for (int m = 0; m < 4; ++m) {
                float a = fmaf(xm[m][0], w0, fmaf(xm[m][1], w1, fmaf(xm[m][2], w2, bk)));
                v[m] = sinf(W0F * a);
            }
            *(float4*)&hA[k][p0] = make_float4(v[0], v[1], v[2], v[3]);
        }
    }

    // ---- hidden layers ----
    for (int l = 0; l < NDEPTH; ++l) {
        const float* Wl = W_h + (size_t)(r * NDEPTH + l) * HDIM * HDIM;
        const float* bl = b_h + (r * NDEPTH + l) * HDIM;
        float accv[4][8];
        #pragma unroll
        for (int m = 0; m < 4; ++m)
            #pragma unroll
            for (int kc = 0; kc < 8; ++kc) accv[m][kc] = 0.f;

        for (int s = 0; s < HDIM / STRIP; ++s) {
            __syncthreads();   // previous strip compute / prev-layer Ws reads done
            // load 32x128 W strip (linear copy, coalesced float4)
            #pragma unroll
            for (int i = 0; i < (STRIP * HDIM) / (256 * 4); ++i) {
                int off = (i * 256 + tid) * 4;
                *(float4*)&Ws[off] = *(const float4*)(Wl + (size_t)s * STRIP * HDIM + off);
            }
            if (s == 0)
                for (int i = tid; i < HDIM; i += 256) bias[i] = bl[i];
            __syncthreads();

            #pragma unroll 8
            for (int j = 0; j < STRIP; ++j) {
                int jj = s * STRIP + j;
                float4 a4 = *(const float4*)&hA[jj][p0];
                float4 wA = *(const float4*)&Ws[j * HDIM + k0];
                float4 wB = *(const float4*)&Ws[j * HDIM + k0 + 4];
                float av[4] = {a4.x, a4.y, a4.z, a4.w};
                float wv[8] = {wA.x, wA.y, wA.z, wA.w, wB.x, wB.y, wB.z, wB.w};
                #pragma unroll
                for (int m = 0; m < 4; ++m)
                    #pragma unroll
                    for (int kc = 0; kc < 8; ++kc)
                        accv[m][kc] = fmaf(av[m], wv[kc], accv[m][kc]);
            }
        }
        __syncthreads();   // all hA reads for this layer complete
        #pragma unroll
        for (int kc = 0; kc < 8; ++kc) {
            int k = k0 + kc;
            float bk = bias[k];
            float v[4];
            #pragma unroll
            for (int m = 0; m < 4; ++m)
                v[m] = sinf(W0F * (accv[m][kc] + bk));
            *(float4*)&hA[k][p0] = make_float4(v[0], v[1], v[2], v[3]);
        }
    }
    __syncthreads();

    // ---- output layer: vis = h @ W_out + b_out ----
    if (tid < HDIM) Ws[tid] = W_out[r * HDIM + tid];
    __syncthreads();
    if (tid < TP) {
        float sacc = 0.f;
        #pragma unroll 8
        for (int k = 0; k < HDIM; ++k)
            sacc = fmaf(hA[k][tid], Ws[k], sacc);
        sacc += b_out[r];
        int g = gidx[tid];
        if (g >= 0) out[g] = sacc;
    }
}

// ---------------- launcher ----------------

extern "C" void kernel_launch(void* const* d_in, const int* in_sizes, int n_in,
                              void* d_out, int out_size, void* d_ws, size_t ws_size,
                              hipStream_t stream) {
    const float* x      = (const float*)d_in[0];
    const float* W_in   = (const float*)d_in[1];
    const float* b_in   = (const float*)d_in[2];
    const float* W_h    = (const float*)d_in[3];
    const float* b_h    = (const float*)d_in[4];
    const float* W_out  = (const float*)d_in[5];
    const float* b_out  = (const float*)d_in[6];
    const float* scale  = (const float*)d_in[7];
    const float* boxes  = (const float*)d_in[8];
    float* out = (float*)d_out;

    int n = in_sizes[0] / 3;
    int* wsi = (int*)d_ws;
    int* idx = (int*)((char*)d_ws + 256);

    hipMemsetAsync(d_ws, 0, 256, stream);

    int nb = (n + 255) / 256;
    hipLaunchKernelGGL(k_count,   dim3(nb), dim3(256), 0, stream, x, n, wsi);
    hipLaunchKernelGGL(k_prefix,  dim3(1),  dim3(64),  0, stream, wsi);
    hipLaunchKernelGGL(k_scatter, dim3(nb), dim3(256), 0, stream, x, n, wsi, idx, out);

    int ntiles = (n + TP - 1) / TP + NREG;
    hipLaunchKernelGGL(k_mlp, dim3(ntiles), dim3(256), 0, stream,
                       x, W_in, b_in, W_h, b_h, W_out, b_out, scale, boxes,
                       wsi + 8, idx, out);
}